// Round 1
// baseline (31.716 us; speedup 1.0000x reference)
//
#include <hip/hip_runtime.h>

// GAE backward recurrence:
//   adv[t] = delta[t] + c[t] * adv[t+1],  c[t] = (1-first[t+1])*gamma*lambda
//   delta[t] = r[t] + (1-first[t+1])*gamma*V[t+1] - V[t]
// Parallelized per-env via linear-function composition (suffix scan).
// One block per env, 256 threads, 8 timesteps per thread.

constexpr int NE   = 4096;
constexpr int NT   = 2048;
constexpr int NT1  = 2049;
constexpr float GAMMA  = 0.99f;
constexpr float LAMBDA = 0.95f;
constexpr int TPB = 256;
constexpr int PER = NT / TPB;   // 8 timesteps per thread

__global__ __launch_bounds__(TPB) void gae_kernel(
    const float* __restrict__ rewards,   // [NE, NT]
    const float* __restrict__ values,    // [NE, NT+1]
    const float* __restrict__ first,     // [NE, NT+1]
    float* __restrict__ out)             // [adv(NE*NT), vtarg(NE*NT)]
{
    const int e   = blockIdx.x;
    const int tid = threadIdx.x;
    const int t0  = tid * PER;

    const float* r_row = rewards + (size_t)e * NT;
    const float* v_row = values  + (size_t)e * NT1;
    const float* f_row = first   + (size_t)e * NT1;

    // rewards rows are 16B-aligned (NT multiple of 4, t0 multiple of 8)
    float r[PER];
    {
        const float4 ra = *reinterpret_cast<const float4*>(r_row + t0);
        const float4 rb = *reinterpret_cast<const float4*>(r_row + t0 + 4);
        r[0]=ra.x; r[1]=ra.y; r[2]=ra.z; r[3]=ra.w;
        r[4]=rb.x; r[5]=rb.y; r[6]=rb.z; r[7]=rb.w;
    }

    // values/first rows have length 2049 -> alignment varies with env; scalar loads
    float v[PER + 1];
#pragma unroll
    for (int k = 0; k <= PER; ++k) v[k] = v_row[t0 + k];

    float c[PER], d[PER];
#pragma unroll
    for (int k = 0; k < PER; ++k) {
        const float nl = 1.0f - f_row[t0 + 1 + k];
        d[k] = r[k] + nl * GAMMA * v[k + 1] - v[k];
        c[k] = nl * (GAMMA * LAMBDA);
    }

    // Local backward pass with incoming adv = 0:
    //   adv[t0] = B + A * adv_in  (A = prod c, B = local result)
    float A = 1.0f, B = 0.0f;
#pragma unroll
    for (int k = PER - 1; k >= 0; --k) {
        B = d[k] + c[k] * B;
        A *= c[k];
    }

    // Inclusive suffix scan of linear functions over the block.
    // Composition: (f1∘f2)(x) = A1*(A2*x+B2)+B1 = (A1*A2)x + (A1*B2+B1)
    __shared__ float sA[TPB];
    __shared__ float sB[TPB];
    float cA = A, cB = B;
#pragma unroll
    for (int off = 1; off < TPB; off <<= 1) {
        sA[tid] = cA;
        sB[tid] = cB;
        __syncthreads();
        if (tid + off < TPB) {
            const float a2 = sA[tid + off];
            const float b2 = sB[tid + off];
            cB = cA * b2 + cB;
            cA = cA * a2;
        }
        __syncthreads();
    }

    // Incoming adv for this segment = inclusive suffix result of thread tid+1
    sB[tid] = cB;
    __syncthreads();
    const float adv_in = (tid + 1 < TPB) ? sB[tid + 1] : 0.0f;

    // Replay local recurrence with the true incoming value.
    float adv[PER];
    float x = adv_in;
#pragma unroll
    for (int k = PER - 1; k >= 0; --k) {
        x = d[k] + c[k] * x;
        adv[k] = x;
    }

    float* adv_out = out + (size_t)e * NT + t0;
    float* vt_out  = out + (size_t)NE * NT + (size_t)e * NT + t0;
    *reinterpret_cast<float4*>(adv_out)     = make_float4(adv[0], adv[1], adv[2], adv[3]);
    *reinterpret_cast<float4*>(adv_out + 4) = make_float4(adv[4], adv[5], adv[6], adv[7]);
    *reinterpret_cast<float4*>(vt_out)      = make_float4(v[0]+adv[0], v[1]+adv[1], v[2]+adv[2], v[3]+adv[3]);
    *reinterpret_cast<float4*>(vt_out + 4)  = make_float4(v[4]+adv[4], v[5]+adv[5], v[6]+adv[6], v[7]+adv[7]);
}

extern "C" void kernel_launch(void* const* d_in, const int* in_sizes, int n_in,
                              void* d_out, int out_size, void* d_ws, size_t ws_size,
                              hipStream_t stream) {
    const float* rewards = (const float*)d_in[0];
    const float* values  = (const float*)d_in[1];
    const float* first   = (const float*)d_in[2];
    float* out = (float*)d_out;
    gae_kernel<<<NE, TPB, 0, stream>>>(rewards, values, first, out);
}

// Round 2
// 30.417 us; speedup vs baseline: 1.0427x; 1.0427x over previous
//
#include <hip/hip_runtime.h>

// GAE backward recurrence, coalesced version.
//   adv[t] = delta[t] + c[t] * adv[t+1],  c[t] = (1-first[t+1])*gamma*lambda
//   delta[t] = r[t] + (1-first[t+1])*gamma*V[t+1] - V[t]
// One block per env. Phase 1: coalesced loads -> delta/c in padded LDS.
// Phase 2: per-thread contiguous segment + block suffix scan of (A,B).
// Phase 3: coalesced stores of adv and v_targ.

constexpr int NE   = 4096;
constexpr int NT   = 2048;
constexpr int NT1  = 2049;
constexpr float GAMMA  = 0.99f;
constexpr float LAMBDA = 0.95f;
constexpr int TPB = 256;
constexpr int PER = NT / TPB;   // 8 timesteps per thread

__device__ __forceinline__ int pad(int i) { return i + (i >> 5); }
constexpr int LDSN = NT + (NT >> 5);   // 2112

__global__ __launch_bounds__(TPB) void gae_kernel(
    const float* __restrict__ rewards,   // [NE, NT]
    const float* __restrict__ values,    // [NE, NT+1]
    const float* __restrict__ first,     // [NE, NT+1]
    float* __restrict__ out)             // [adv(NE*NT), vtarg(NE*NT)]
{
    __shared__ float d_lds[LDSN];
    __shared__ float c_lds[LDSN];
    __shared__ float sA[TPB];
    __shared__ float sB[TPB];

    const int e   = blockIdx.x;
    const int tid = threadIdx.x;

    const float* r_row = rewards + (size_t)e * NT;
    const float* v_row = values  + (size_t)e * NT1;
    const float* f_row = first   + (size_t)e * NT1;

    // ---- Phase 1: coalesced loads, compute delta/c into LDS ----
    float vreg[PER];
#pragma unroll
    for (int j = 0; j < PER; ++j) {
        const int t = j * TPB + tid;
        const float v0 = v_row[t];
        const float v1 = v_row[t + 1];
        const float f1 = f_row[t + 1];
        const float rr = r_row[t];
        vreg[j] = v0;
        const float nl = 1.0f - f1;
        d_lds[pad(t)] = rr + nl * GAMMA * v1 - v0;
        c_lds[pad(t)] = nl * (GAMMA * LAMBDA);
    }
    __syncthreads();

    // ---- Phase 2: per-thread contiguous segment ----
    const int t0 = tid * PER;
    float d[PER], c[PER];
#pragma unroll
    for (int k = 0; k < PER; ++k) {
        d[k] = d_lds[pad(t0 + k)];
        c[k] = c_lds[pad(t0 + k)];
    }

    // Local backward pass with incoming adv = 0: result = B, gain = A
    float A = 1.0f, B = 0.0f;
#pragma unroll
    for (int k = PER - 1; k >= 0; --k) {
        B = d[k] + c[k] * B;
        A *= c[k];
    }

    // Inclusive suffix scan of linear functions over the block.
    float cA = A, cB = B;
#pragma unroll
    for (int off = 1; off < TPB; off <<= 1) {
        sA[tid] = cA;
        sB[tid] = cB;
        __syncthreads();
        if (tid + off < TPB) {
            const float a2 = sA[tid + off];
            const float b2 = sB[tid + off];
            cB = cA * b2 + cB;
            cA = cA * a2;
        }
        __syncthreads();
    }
    sB[tid] = cB;
    __syncthreads();
    const float adv_in = (tid + 1 < TPB) ? sB[tid + 1] : 0.0f;

    // Replay local recurrence; stash adv back into d_lds (own slots only).
    float x = adv_in;
#pragma unroll
    for (int k = PER - 1; k >= 0; --k) {
        x = d[k] + c[k] * x;
        d[k] = x;
    }
#pragma unroll
    for (int k = 0; k < PER; ++k) d_lds[pad(t0 + k)] = d[k];
    __syncthreads();

    // ---- Phase 3: coalesced stores ----
    float* __restrict__ adv_out = out + (size_t)e * NT;
    float* __restrict__ vt_out  = out + (size_t)NE * NT + (size_t)e * NT;
#pragma unroll
    for (int j = 0; j < PER; ++j) {
        const int t = j * TPB + tid;
        const float a = d_lds[pad(t)];
        adv_out[t] = a;
        vt_out[t]  = vreg[j] + a;
    }
}

extern "C" void kernel_launch(void* const* d_in, const int* in_sizes, int n_in,
                              void* d_out, int out_size, void* d_ws, size_t ws_size,
                              hipStream_t stream) {
    const float* rewards = (const float*)d_in[0];
    const float* values  = (const float*)d_in[1];
    const float* first   = (const float*)d_in[2];
    float* out = (float*)d_out;
    gae_kernel<<<NE, TPB, 0, stream>>>(rewards, values, first, out);
}

// Round 4
// 30.046 us; speedup vs baseline: 1.0556x; 1.0123x over previous
//
#include <hip/hip_runtime.h>

// GAE backward recurrence, v3b (nontemporal-store fix).
//   adv[t] = delta[t] + c[t] * adv[t+1],  c[t] = (1-first[t+1])*gamma*lambda
//   delta[t] = r[t] + (1-first[t+1])*gamma*V[t+1] - V[t]
// One block per env (4096 blocks x 256 threads).
//  Phase 1: coalesced loads (float4 rewards), delta/c -> XOR-swizzled LDS float4 granules.
//  Phase 2: per-thread 8-step segment; wave-level shuffle suffix scan of linear
//           functions (A,B); 4 wave totals combined via 16B LDS. 3 barriers total.
//  Phase 3: nontemporal float4 stores of adv and v_targ (don't pollute L3 --
//           inputs stay resident across graph replays).

constexpr int NE   = 4096;
constexpr int NT   = 2048;
constexpr int NT1  = 2049;
constexpr float GAMMA  = 0.99f;
constexpr float LAMBDA = 0.95f;
constexpr int TPB = 256;
constexpr int PER = NT / TPB;    // 8 timesteps per thread (phase 2 segment)
constexpr int NQ  = NT / 4;      // 512 float4 granules per env
constexpr int QPT = NQ / TPB;    // 2 granules per thread (phases 1 & 3)

typedef float f32x4 __attribute__((ext_vector_type(4)));  // native vector for NT stores

// 16B-granule XOR swizzle: conflict-free for both lane-consecutive granule
// access (phases 1/3) and lane-stride-2 granule access (phase 2).
__device__ __forceinline__ int swz(int g) { return g ^ ((g >> 3) & 7); }

__global__ __launch_bounds__(TPB) void gae_kernel(
    const float* __restrict__ rewards,   // [NE, NT]
    const float* __restrict__ values,    // [NE, NT+1]
    const float* __restrict__ first,     // [NE, NT+1]
    float* __restrict__ out)             // [adv(NE*NT), vtarg(NE*NT)]
{
    __shared__ float4 d_lds[NQ];   // delta, later adv
    __shared__ float4 c_lds[NQ];   // decay coefficient
    __shared__ float  sWA[4];      // per-wave scan totals
    __shared__ float  sWB[4];

    const int e    = blockIdx.x;
    const int tid  = threadIdx.x;
    const int lane = tid & 63;
    const int w    = tid >> 6;

    const float* r_row = rewards + (size_t)e * NT;
    const float* v_row = values  + (size_t)e * NT1;
    const float* f_row = first   + (size_t)e * NT1;

    // ---- Phase 1: compute delta/c into swizzled LDS granules ----
    float4 vreg[QPT];
#pragma unroll
    for (int j = 0; j < QPT; ++j) {
        const int q = j * TPB + tid;
        const int t = 4 * q;
        const float4 r4 = *reinterpret_cast<const float4*>(r_row + t);
        const float v0 = v_row[t + 0];
        const float v1 = v_row[t + 1];
        const float v2 = v_row[t + 2];
        const float v3 = v_row[t + 3];
        const float v4 = v_row[t + 4];
        const float n0 = 1.0f - f_row[t + 1];
        const float n1 = 1.0f - f_row[t + 2];
        const float n2 = 1.0f - f_row[t + 3];
        const float n3 = 1.0f - f_row[t + 4];
        vreg[j] = make_float4(v0, v1, v2, v3);
        float4 d4, c4;
        d4.x = r4.x + n0 * GAMMA * v1 - v0;  c4.x = n0 * (GAMMA * LAMBDA);
        d4.y = r4.y + n1 * GAMMA * v2 - v1;  c4.y = n1 * (GAMMA * LAMBDA);
        d4.z = r4.z + n2 * GAMMA * v3 - v2;  c4.z = n2 * (GAMMA * LAMBDA);
        d4.w = r4.w + n3 * GAMMA * v4 - v3;  c4.w = n3 * (GAMMA * LAMBDA);
        d_lds[swz(q)] = d4;
        c_lds[swz(q)] = c4;
    }
    __syncthreads();

    // ---- Phase 2: per-thread contiguous 8-step segment ----
    float d[PER], c[PER];
    {
        const float4 da = d_lds[swz(2 * tid)];
        const float4 db = d_lds[swz(2 * tid + 1)];
        const float4 ca = c_lds[swz(2 * tid)];
        const float4 cb = c_lds[swz(2 * tid + 1)];
        d[0]=da.x; d[1]=da.y; d[2]=da.z; d[3]=da.w;
        d[4]=db.x; d[5]=db.y; d[6]=db.z; d[7]=db.w;
        c[0]=ca.x; c[1]=ca.y; c[2]=ca.z; c[3]=ca.w;
        c[4]=cb.x; c[5]=cb.y; c[6]=cb.z; c[7]=cb.w;
    }

    // Local linear function: x -> A*x + B (incoming adv -> adv at segment head)
    float A = 1.0f, B = 0.0f;
#pragma unroll
    for (int k = PER - 1; k >= 0; --k) {
        B = fmaf(c[k], B, d[k]);
        A *= c[k];
    }

    // Wave-level inclusive suffix scan via shuffles (no barriers).
    float cA = A, cB = B;
#pragma unroll
    for (int off = 1; off < 64; off <<= 1) {
        const float a2 = __shfl_down(cA, off);
        const float b2 = __shfl_down(cB, off);
        if (lane + off < 64) {
            cB = fmaf(cA, b2, cB);
            cA = cA * a2;
        }
    }

    // Wave totals -> LDS (lane 0 holds the whole-wave composition).
    if (lane == 0) { sWA[w] = cA; sWB[w] = cB; }

    // Exclusive-within-wave (suffix from lane+1).
    float EA = __shfl_down(cA, 1);
    float EB = __shfl_down(cB, 1);
    if (lane == 63) { EA = 1.0f; EB = 0.0f; }

    __syncthreads();

    // Tail composition of later waves: T = W_{w+1} o W_{w+2} o W_{w+3}.
    float TB = 0.0f;
    for (int u = 3; u > w; --u) {
        TB = fmaf(sWA[u], TB, sWB[u]);
    }
    // Incoming adv for this thread's segment: (E o T)(0) = EA*TB + EB
    float x = fmaf(EA, TB, EB);

    // Replay local recurrence with the true incoming value; stash adv in LDS.
    float adv[PER];
#pragma unroll
    for (int k = PER - 1; k >= 0; --k) {
        x = fmaf(c[k], x, d[k]);
        adv[k] = x;
    }
    d_lds[swz(2 * tid)]     = make_float4(adv[0], adv[1], adv[2], adv[3]);
    d_lds[swz(2 * tid + 1)] = make_float4(adv[4], adv[5], adv[6], adv[7]);
    __syncthreads();

    // ---- Phase 3: nontemporal coalesced float4 stores ----
    float* __restrict__ adv_out = out + (size_t)e * NT;
    float* __restrict__ vt_out  = out + (size_t)NE * NT + (size_t)e * NT;
#pragma unroll
    for (int j = 0; j < QPT; ++j) {
        const int q = j * TPB + tid;
        const int t = 4 * q;
        const float4 a4 = d_lds[swz(q)];
        const float4 v4 = vreg[j];
        f32x4 av; av.x = a4.x; av.y = a4.y; av.z = a4.z; av.w = a4.w;
        f32x4 vt; vt.x = v4.x + a4.x; vt.y = v4.y + a4.y;
                  vt.z = v4.z + a4.z; vt.w = v4.w + a4.w;
        __builtin_nontemporal_store(av, reinterpret_cast<f32x4*>(adv_out + t));
        __builtin_nontemporal_store(vt, reinterpret_cast<f32x4*>(vt_out + t));
    }
}

extern "C" void kernel_launch(void* const* d_in, const int* in_sizes, int n_in,
                              void* d_out, int out_size, void* d_ws, size_t ws_size,
                              hipStream_t stream) {
    const float* rewards = (const float*)d_in[0];
    const float* values  = (const float*)d_in[1];
    const float* first   = (const float*)d_in[2];
    float* out = (float*)d_out;
    gae_kernel<<<NE, TPB, 0, stream>>>(rewards, values, first, out);
}

// Round 5
// 30.008 us; speedup vs baseline: 1.0569x; 1.0013x over previous
//
#include <hip/hip_runtime.h>

// GAE backward recurrence, v4 (vectorized values/first loads).
//   adv[t] = delta[t] + c[t] * adv[t+1],  c[t] = (1-first[t+1])*gamma*lambda
//   delta[t] = r[t] + (1-first[t+1])*gamma*V[t+1] - V[t]
// One block per env (4096 blocks x 256 threads).
//  Phase 1: all-float4 coalesced loads (values/first via align(4) dwordx4 --
//           rows are length 2049 so base alignment varies per env; gfx950
//           supports unaligned multi-dword VMEM), delta/c -> swizzled LDS.
//  Phase 2: per-thread 8-step segment; wave-level shuffle suffix scan of
//           linear functions (A,B); 4 wave totals via 16B LDS. 3 barriers.
//  Phase 3: nontemporal coalesced float4 stores of adv and v_targ.

constexpr int NE   = 4096;
constexpr int NT   = 2048;
constexpr int NT1  = 2049;
constexpr float GAMMA  = 0.99f;
constexpr float LAMBDA = 0.95f;
constexpr int TPB = 256;
constexpr int PER = NT / TPB;    // 8 timesteps per thread (phase 2 segment)
constexpr int NQ  = NT / 4;      // 512 float4 granules per env
constexpr int QPT = NQ / TPB;    // 2 granules per thread (phases 1 & 3)

typedef float f32x4 __attribute__((ext_vector_type(4)));
typedef float f32x4u __attribute__((ext_vector_type(4), aligned(4)));  // unaligned ld

__device__ __forceinline__ f32x4 ld4u(const float* p) {
    return (f32x4)*reinterpret_cast<const f32x4u*>(p);
}

// 16B-granule XOR swizzle: <=2-way (free) for both lane-consecutive granule
// access (phases 1/3) and lane-stride-2 granule access (phase 2).
__device__ __forceinline__ int swz(int g) { return g ^ ((g >> 3) & 7); }

__global__ __launch_bounds__(TPB) void gae_kernel(
    const float* __restrict__ rewards,   // [NE, NT]
    const float* __restrict__ values,    // [NE, NT+1]
    const float* __restrict__ first,     // [NE, NT+1]
    float* __restrict__ out)             // [adv(NE*NT), vtarg(NE*NT)]
{
    __shared__ f32x4 d_lds[NQ];   // delta, later adv
    __shared__ f32x4 c_lds[NQ];   // decay coefficient
    __shared__ float sWA[4];      // per-wave scan totals
    __shared__ float sWB[4];

    const int e    = blockIdx.x;
    const int tid  = threadIdx.x;
    const int lane = tid & 63;
    const int w    = tid >> 6;

    const float* r_row = rewards + (size_t)e * NT;
    const float* v_row = values  + (size_t)e * NT1;
    const float* f_row = first   + (size_t)e * NT1;

    // ---- Phase 1: all-vector loads, delta/c into swizzled LDS ----
    f32x4 vreg[QPT];
#pragma unroll
    for (int j = 0; j < QPT; ++j) {
        const int q = j * TPB + tid;
        const int t = 4 * q;
        const f32x4 r4  = *reinterpret_cast<const f32x4*>(r_row + t);  // 16B aligned
        const f32x4 v4a = ld4u(v_row + t);       // v[t..t+3]
        const f32x4 v4b = ld4u(v_row + t + 1);   // v[t+1..t+4]
        const f32x4 f4  = ld4u(f_row + t + 1);   // f[t+1..t+4]
        vreg[j] = v4a;
        const f32x4 nl = 1.0f - f4;
        f32x4 d4, c4;
        d4 = r4 + nl * GAMMA * v4b - v4a;
        c4 = nl * (GAMMA * LAMBDA);
        d_lds[swz(q)] = d4;
        c_lds[swz(q)] = c4;
    }
    __syncthreads();

    // ---- Phase 2: per-thread contiguous 8-step segment ----
    float d[PER], c[PER];
    {
        const f32x4 da = d_lds[swz(2 * tid)];
        const f32x4 db = d_lds[swz(2 * tid + 1)];
        const f32x4 ca = c_lds[swz(2 * tid)];
        const f32x4 cb = c_lds[swz(2 * tid + 1)];
        d[0]=da.x; d[1]=da.y; d[2]=da.z; d[3]=da.w;
        d[4]=db.x; d[5]=db.y; d[6]=db.z; d[7]=db.w;
        c[0]=ca.x; c[1]=ca.y; c[2]=ca.z; c[3]=ca.w;
        c[4]=cb.x; c[5]=cb.y; c[6]=cb.z; c[7]=cb.w;
    }

    // Local linear function: x -> A*x + B (incoming adv -> adv at segment head)
    float A = 1.0f, B = 0.0f;
#pragma unroll
    for (int k = PER - 1; k >= 0; --k) {
        B = fmaf(c[k], B, d[k]);
        A *= c[k];
    }

    // Wave-level inclusive suffix scan via shuffles (no barriers).
    float cA = A, cB = B;
#pragma unroll
    for (int off = 1; off < 64; off <<= 1) {
        const float a2 = __shfl_down(cA, off);
        const float b2 = __shfl_down(cB, off);
        if (lane + off < 64) {
            cB = fmaf(cA, b2, cB);
            cA = cA * a2;
        }
    }

    // Wave totals -> LDS (lane 0 holds the whole-wave composition).
    if (lane == 0) { sWA[w] = cA; sWB[w] = cB; }

    // Exclusive-within-wave (suffix from lane+1).
    float EA = __shfl_down(cA, 1);
    float EB = __shfl_down(cB, 1);
    if (lane == 63) { EA = 1.0f; EB = 0.0f; }

    __syncthreads();

    // Tail composition of later waves: T = W_{w+1} o W_{w+2} o W_{w+3}.
    float TB = 0.0f;
    for (int u = 3; u > w; --u) {
        TB = fmaf(sWA[u], TB, sWB[u]);
    }
    // Incoming adv for this thread's segment: (E o T)(0) = EA*TB + EB
    float x = fmaf(EA, TB, EB);

    // Replay local recurrence; stash adv back into d_lds (own slots only).
    float adv[PER];
#pragma unroll
    for (int k = PER - 1; k >= 0; --k) {
        x = fmaf(c[k], x, d[k]);
        adv[k] = x;
    }
    {
        f32x4 a0; a0.x=adv[0]; a0.y=adv[1]; a0.z=adv[2]; a0.w=adv[3];
        f32x4 a1; a1.x=adv[4]; a1.y=adv[5]; a1.z=adv[6]; a1.w=adv[7];
        d_lds[swz(2 * tid)]     = a0;
        d_lds[swz(2 * tid + 1)] = a1;
    }
    __syncthreads();

    // ---- Phase 3: nontemporal coalesced float4 stores ----
    float* __restrict__ adv_out = out + (size_t)e * NT;
    float* __restrict__ vt_out  = out + (size_t)NE * NT + (size_t)e * NT;
#pragma unroll
    for (int j = 0; j < QPT; ++j) {
        const int q = j * TPB + tid;
        const int t = 4 * q;
        const f32x4 a4 = d_lds[swz(q)];
        const f32x4 vt = vreg[j] + a4;
        __builtin_nontemporal_store(a4, reinterpret_cast<f32x4*>(adv_out + t));
        __builtin_nontemporal_store(vt, reinterpret_cast<f32x4*>(vt_out + t));
    }
}

extern "C" void kernel_launch(void* const* d_in, const int* in_sizes, int n_in,
                              void* d_out, int out_size, void* d_ws, size_t ws_size,
                              hipStream_t stream) {
    const float* rewards = (const float*)d_in[0];
    const float* values  = (const float*)d_in[1];
    const float* first   = (const float*)d_in[2];
    float* out = (float*)d_out;
    gae_kernel<<<NE, TPB, 0, stream>>>(rewards, values, first, out);
}